// Round 1
// baseline (282.548 us; speedup 1.0000x reference)
//
#include <hip/hip_runtime.h>
#include <hip/hip_bf16.h>

#define N_NODES 100000
#define N_EDGES 1600000
#define IN_F 256
#define OUT_F 64

// ---------------------------------------------------------------------------
// Kernel 1: build CSR row pointers from sorted row_idx via binary search.
// row_ptr[i] = lower_bound(row_idx, i); row_ptr[N_NODES] = N_EDGES.
// ---------------------------------------------------------------------------
__global__ __launch_bounds__(256) void build_row_ptr_kernel(
    const int* __restrict__ row_idx, int* __restrict__ row_ptr) {
  int i = blockIdx.x * blockDim.x + threadIdx.x;
  if (i > N_NODES) return;
  int lo = 0, hi = N_EDGES;
  while (lo < hi) {
    int mid = (lo + hi) >> 1;
    if (row_idx[mid] < i) lo = mid + 1; else hi = mid;
  }
  row_ptr[i] = lo;
}

// ---------------------------------------------------------------------------
// Kernel 2: support = x @ W   (fp32, [N_NODES,256] x [256,64])
// W staged fully in LDS (64 KB). One wave computes 4 rows; lane = out feature.
// Per k-quad: 4 LDS reads of W (shared across 4 rows) + 4 broadcast float4
// x loads + 16 FMAs. 4 independent acc chains -> pipelined VALU.
// ---------------------------------------------------------------------------
__global__ __launch_bounds__(256) void gemm_kernel(
    const float* __restrict__ x, const float* __restrict__ W,
    float* __restrict__ support) {
  __shared__ float sW[IN_F * OUT_F];  // 64 KB
  {
    const float4* W4 = reinterpret_cast<const float4*>(W);
    float4* sW4 = reinterpret_cast<float4*>(sW);
    for (int i = threadIdx.x; i < IN_F * OUT_F / 4; i += 256) sW4[i] = W4[i];
  }
  __syncthreads();

  const int lane = threadIdx.x & 63;
  const int wave = threadIdx.x >> 6;
  const int gwave = blockIdx.x * 4 + wave;
  const int nwaves = gridDim.x * 4;

  for (int r0 = gwave * 4; r0 < N_NODES; r0 += nwaves * 4) {
    const int r1 = (r0 + 1 < N_NODES) ? r0 + 1 : N_NODES - 1;
    const int r2 = (r0 + 2 < N_NODES) ? r0 + 2 : N_NODES - 1;
    const int r3 = (r0 + 3 < N_NODES) ? r0 + 3 : N_NODES - 1;
    const float4* xr0 = reinterpret_cast<const float4*>(x + (size_t)r0 * IN_F);
    const float4* xr1 = reinterpret_cast<const float4*>(x + (size_t)r1 * IN_F);
    const float4* xr2 = reinterpret_cast<const float4*>(x + (size_t)r2 * IN_F);
    const float4* xr3 = reinterpret_cast<const float4*>(x + (size_t)r3 * IN_F);

    float acc0 = 0.f, acc1 = 0.f, acc2 = 0.f, acc3 = 0.f;
#pragma unroll 8
    for (int k4 = 0; k4 < IN_F / 4; ++k4) {
      const float4 a0 = xr0[k4];
      const float4 a1 = xr1[k4];
      const float4 a2 = xr2[k4];
      const float4 a3 = xr3[k4];
      const float w0 = sW[(k4 * 4 + 0) * OUT_F + lane];
      const float w1 = sW[(k4 * 4 + 1) * OUT_F + lane];
      const float w2 = sW[(k4 * 4 + 2) * OUT_F + lane];
      const float w3 = sW[(k4 * 4 + 3) * OUT_F + lane];
      acc0 = fmaf(a0.x, w0, acc0); acc0 = fmaf(a0.y, w1, acc0);
      acc0 = fmaf(a0.z, w2, acc0); acc0 = fmaf(a0.w, w3, acc0);
      acc1 = fmaf(a1.x, w0, acc1); acc1 = fmaf(a1.y, w1, acc1);
      acc1 = fmaf(a1.z, w2, acc1); acc1 = fmaf(a1.w, w3, acc1);
      acc2 = fmaf(a2.x, w0, acc2); acc2 = fmaf(a2.y, w1, acc2);
      acc2 = fmaf(a2.z, w2, acc2); acc2 = fmaf(a2.w, w3, acc2);
      acc3 = fmaf(a3.x, w0, acc3); acc3 = fmaf(a3.y, w1, acc3);
      acc3 = fmaf(a3.z, w2, acc3); acc3 = fmaf(a3.w, w3, acc3);
    }
    support[(size_t)r0 * OUT_F + lane] = acc0;
    if (r0 + 1 < N_NODES) support[(size_t)(r0 + 1) * OUT_F + lane] = acc1;
    if (r0 + 2 < N_NODES) support[(size_t)(r0 + 2) * OUT_F + lane] = acc2;
    if (r0 + 3 < N_NODES) support[(size_t)(r0 + 3) * OUT_F + lane] = acc3;
  }
}

// ---------------------------------------------------------------------------
// Kernel 3: out[n] = bias + sum_{e in row n} edge_vals[e] * support[col[e]]
// One wave per node (lane = feature). Edges of a node are contiguous
// (row_idx sorted). 4-deep manual unroll keeps 4 gathers in flight per wave.
// No atomics, deterministic.
// ---------------------------------------------------------------------------
__global__ __launch_bounds__(256) void spmm_kernel(
    const float* __restrict__ support, const float* __restrict__ ev,
    const int* __restrict__ col, const int* __restrict__ row_ptr,
    const float* __restrict__ bias, float* __restrict__ out) {
  const int lane = threadIdx.x & 63;
  const int gwave = (blockIdx.x * blockDim.x + threadIdx.x) >> 6;
  const int nwaves = (gridDim.x * blockDim.x) >> 6;
  const float b = bias[lane];

  for (int node = gwave; node < N_NODES; node += nwaves) {
    const int s = row_ptr[node];
    const int e = row_ptr[node + 1];
    float acc = 0.f;
    int i = s;
    for (; i + 4 <= e; i += 4) {
      const int c0 = col[i + 0];
      const int c1 = col[i + 1];
      const int c2 = col[i + 2];
      const int c3 = col[i + 3];
      const float v0 = ev[i + 0];
      const float v1 = ev[i + 1];
      const float v2 = ev[i + 2];
      const float v3 = ev[i + 3];
      const float g0 = support[(size_t)c0 * OUT_F + lane];
      const float g1 = support[(size_t)c1 * OUT_F + lane];
      const float g2 = support[(size_t)c2 * OUT_F + lane];
      const float g3 = support[(size_t)c3 * OUT_F + lane];
      acc = fmaf(v0, g0, acc);
      acc = fmaf(v1, g1, acc);
      acc = fmaf(v2, g2, acc);
      acc = fmaf(v3, g3, acc);
    }
    for (; i < e; ++i) {
      acc = fmaf(ev[i], support[(size_t)col[i] * OUT_F + lane], acc);
    }
    out[(size_t)node * OUT_F + lane] = acc + b;
  }
}

extern "C" void kernel_launch(void* const* d_in, const int* in_sizes, int n_in,
                              void* d_out, int out_size, void* d_ws, size_t ws_size,
                              hipStream_t stream) {
  const float* x        = (const float*)d_in[0];
  const float* ev       = (const float*)d_in[1];
  const float* W        = (const float*)d_in[2];
  const float* bias     = (const float*)d_in[3];
  const int*   row_idx  = (const int*)d_in[4];
  const int*   col_idx  = (const int*)d_in[5];
  float* out = (float*)d_out;

  // Workspace layout: [0, ~400KB) row_ptr ints; [512KB, +25.6MB) support fp32.
  int*   row_ptr = (int*)d_ws;
  float* support = (float*)((char*)d_ws + (1 << 19));

  // Kernel 1: row pointers (100001 threads).
  build_row_ptr_kernel<<<(N_NODES + 1 + 255) / 256, 256, 0, stream>>>(row_idx, row_ptr);

  // Kernel 2: dense GEMM. 512 persistent blocks (2/CU with 64KB LDS each).
  gemm_kernel<<<512, 256, 0, stream>>>(x, W, support);

  // Kernel 3: gather + segment-sum + bias. 2048 blocks x 256 (8192 waves).
  spmm_kernel<<<2048, 256, 0, stream>>>(support, ev, col_idx, row_ptr, bias, out);
}

// Round 2
// 102.366 us; speedup vs baseline: 2.7602x; 2.7602x over previous
//
#include <hip/hip_runtime.h>
#include <hip/hip_bf16.h>

#define N_NODES 100000
#define N_EDGES 1600000
#define IN_F 256
#define OUT_F 64

typedef short bf16x8 __attribute__((ext_vector_type(8)));
typedef float f32x4 __attribute__((ext_vector_type(4)));

__device__ __forceinline__ short f2bf(float f) {
  unsigned u = __float_as_uint(f);
  u += 0x7FFF + ((u >> 16) & 1);  // round-to-nearest-even
  return (short)(u >> 16);
}

// ---------------------------------------------------------------------------
// Kernel 1: CSR row pointers from sorted row_idx (binary search).
// ---------------------------------------------------------------------------
__global__ __launch_bounds__(256) void build_row_ptr_kernel(
    const int* __restrict__ row_idx, int* __restrict__ row_ptr) {
  int i = blockIdx.x * blockDim.x + threadIdx.x;
  if (i > N_NODES) return;
  int lo = 0, hi = N_EDGES;
  while (lo < hi) {
    int mid = (lo + hi) >> 1;
    if (row_idx[mid] < i) lo = mid + 1; else hi = mid;
  }
  row_ptr[i] = lo;
}

// ---------------------------------------------------------------------------
// Kernel 1b: precompute W as bf16 MFMA B-fragments, fragment-major.
// For K-step s (8), col-tile t (4), lane l (64), elem j (8):
//   k = s*32 + (l>>4)*8 + j, col = t*16 + (l&15)
//   Wf[((s*4+t)*64 + l)*8 + j] = bf16(W[k*64+col])
// So in the GEMM a B fragment is one contiguous 16B ds_read_b128 per lane.
// ---------------------------------------------------------------------------
__global__ __launch_bounds__(256) void wfrag_kernel(
    const float* __restrict__ W, short* __restrict__ Wf) {
  int tid = blockIdx.x * blockDim.x + threadIdx.x;  // [0, 2048)
  if (tid >= 2048) return;
  int s = tid >> 8;
  int r = tid & 255;
  int t = r >> 6;
  int lane = r & 63;
  int col = t * 16 + (lane & 15);
  int kbase = s * 32 + ((lane >> 4) & 3) * 8;
#pragma unroll
  for (int j = 0; j < 8; ++j) {
    Wf[(size_t)tid * 8 + j] = f2bf(W[(size_t)(kbase + j) * OUT_F + col]);
  }
}

// ---------------------------------------------------------------------------
// Kernel 2: support = x @ W via bf16 MFMA (16x16x32).
// Block = 256 thr = 4 waves, 64 rows/block. Wave w: rows [b*64+w*16, +16),
// all 64 cols as 4 col-tiles. A-frag loaded from global x (fp32->bf16 in
// reg, same (lane,j)->k placement as Wf so internal k-permutation cancels).
// B-frags from LDS-staged Wf (one ds_read_b128 each).
// C/D layout (HW-verified): col = lane&15, row = (lane>>4)*4 + reg.
// ---------------------------------------------------------------------------
__global__ __launch_bounds__(256) void gemm_kernel(
    const float* __restrict__ x, const short* __restrict__ Wf,
    float* __restrict__ support) {
  __shared__ short sWf[8 * 4 * 64 * 8];  // 32 KB
  {
    const float4* g = reinterpret_cast<const float4*>(Wf);
    float4* s4 = reinterpret_cast<float4*>(sWf);
#pragma unroll
    for (int i = 0; i < 8; ++i) s4[threadIdx.x + i * 256] = g[threadIdx.x + i * 256];
  }
  __syncthreads();

  const int lane = threadIdx.x & 63;
  const int wave = threadIdx.x >> 6;
  const int r0_base = blockIdx.x * 64 + wave * 16;

  // A-frag source row for this lane (clamped; out-of-range rows not stored).
  int arow = r0_base + (lane & 15);
  if (arow >= N_NODES) arow = N_NODES - 1;
  const float* xrow = x + (size_t)arow * IN_F + ((lane >> 4) & 3) * 8;

  f32x4 acc0 = {0.f, 0.f, 0.f, 0.f};
  f32x4 acc1 = {0.f, 0.f, 0.f, 0.f};
  f32x4 acc2 = {0.f, 0.f, 0.f, 0.f};
  f32x4 acc3 = {0.f, 0.f, 0.f, 0.f};

#pragma unroll
  for (int s = 0; s < 8; ++s) {
    const float4 f0 = *reinterpret_cast<const float4*>(xrow + s * 32);
    const float4 f1 = *reinterpret_cast<const float4*>(xrow + s * 32 + 4);
    bf16x8 a;
    a[0] = f2bf(f0.x); a[1] = f2bf(f0.y); a[2] = f2bf(f0.z); a[3] = f2bf(f0.w);
    a[4] = f2bf(f1.x); a[5] = f2bf(f1.y); a[6] = f2bf(f1.z); a[7] = f2bf(f1.w);
    const bf16x8 b0 = *reinterpret_cast<const bf16x8*>(&sWf[((s * 4 + 0) * 64 + lane) * 8]);
    const bf16x8 b1 = *reinterpret_cast<const bf16x8*>(&sWf[((s * 4 + 1) * 64 + lane) * 8]);
    const bf16x8 b2 = *reinterpret_cast<const bf16x8*>(&sWf[((s * 4 + 2) * 64 + lane) * 8]);
    const bf16x8 b3 = *reinterpret_cast<const bf16x8*>(&sWf[((s * 4 + 3) * 64 + lane) * 8]);
    acc0 = __builtin_amdgcn_mfma_f32_16x16x32_bf16(a, b0, acc0, 0, 0, 0);
    acc1 = __builtin_amdgcn_mfma_f32_16x16x32_bf16(a, b1, acc1, 0, 0, 0);
    acc2 = __builtin_amdgcn_mfma_f32_16x16x32_bf16(a, b2, acc2, 0, 0, 0);
    acc3 = __builtin_amdgcn_mfma_f32_16x16x32_bf16(a, b3, acc3, 0, 0, 0);
  }

  const int orow_base = r0_base + ((lane >> 4) & 3) * 4;
  const int ocol = lane & 15;
#pragma unroll
  for (int r = 0; r < 4; ++r) {
    const int row = orow_base + r;
    if (row < N_NODES) {
      float* o = support + (size_t)row * OUT_F + ocol;
      o[0]  = acc0[r];
      o[16] = acc1[r];
      o[32] = acc2[r];
      o[48] = acc3[r];
    }
  }
}

// ---------------------------------------------------------------------------
// Kernel 3: out[n] = bias + sum_{e in row n} ev[e] * support[col[e]]
// One wave per node, lane = feature, no atomics.
// ---------------------------------------------------------------------------
__global__ __launch_bounds__(256) void spmm_kernel(
    const float* __restrict__ support, const float* __restrict__ ev,
    const int* __restrict__ col, const int* __restrict__ row_ptr,
    const float* __restrict__ bias, float* __restrict__ out) {
  const int lane = threadIdx.x & 63;
  const int gwave = (blockIdx.x * blockDim.x + threadIdx.x) >> 6;
  const int nwaves = (gridDim.x * blockDim.x) >> 6;
  const float b = bias[lane];

  for (int node = gwave; node < N_NODES; node += nwaves) {
    const int s = row_ptr[node];
    const int e = row_ptr[node + 1];
    float acc = 0.f;
    int i = s;
    for (; i + 4 <= e; i += 4) {
      const int c0 = col[i + 0];
      const int c1 = col[i + 1];
      const int c2 = col[i + 2];
      const int c3 = col[i + 3];
      const float v0 = ev[i + 0];
      const float v1 = ev[i + 1];
      const float v2 = ev[i + 2];
      const float v3 = ev[i + 3];
      const float g0 = support[(size_t)c0 * OUT_F + lane];
      const float g1 = support[(size_t)c1 * OUT_F + lane];
      const float g2 = support[(size_t)c2 * OUT_F + lane];
      const float g3 = support[(size_t)c3 * OUT_F + lane];
      acc = fmaf(v0, g0, acc);
      acc = fmaf(v1, g1, acc);
      acc = fmaf(v2, g2, acc);
      acc = fmaf(v3, g3, acc);
    }
    for (; i < e; ++i) {
      acc = fmaf(ev[i], support[(size_t)col[i] * OUT_F + lane], acc);
    }
    out[(size_t)node * OUT_F + lane] = acc + b;
  }
}

extern "C" void kernel_launch(void* const* d_in, const int* in_sizes, int n_in,
                              void* d_out, int out_size, void* d_ws, size_t ws_size,
                              hipStream_t stream) {
  const float* x        = (const float*)d_in[0];
  const float* ev       = (const float*)d_in[1];
  const float* W        = (const float*)d_in[2];
  const float* bias     = (const float*)d_in[3];
  const int*   row_idx  = (const int*)d_in[4];
  const int*   col_idx  = (const int*)d_in[5];
  float* out = (float*)d_out;

  // Workspace: [0, 400KB) row_ptr; [448KB, 480KB) W-fragments (bf16);
  //            [512KB, +25.6MB) support fp32.
  int*   row_ptr = (int*)d_ws;
  short* Wf      = (short*)((char*)d_ws + 448 * 1024);
  float* support = (float*)((char*)d_ws + 512 * 1024);

  build_row_ptr_kernel<<<(N_NODES + 1 + 255) / 256, 256, 0, stream>>>(row_idx, row_ptr);
  wfrag_kernel<<<8, 256, 0, stream>>>(W, Wf);

  // GEMM: 64 rows per block.
  gemm_kernel<<<(N_NODES + 63) / 64, 256, 0, stream>>>(x, Wf, support);

  // spmm: 8192 waves.
  spmm_kernel<<<2048, 256, 0, stream>>>(support, ev, col_idx, row_ptr, bias, out);
}

// Round 3
// 79.441 us; speedup vs baseline: 3.5567x; 1.2886x over previous
//
#include <hip/hip_runtime.h>
#include <hip/hip_bf16.h>

#define N_NODES 100000
#define N_EDGES 1600000
#define IN_F 256
#define OUT_F 64

typedef short bf16x8 __attribute__((ext_vector_type(8)));
typedef float f32x4 __attribute__((ext_vector_type(4)));

__device__ __forceinline__ short f2bf(float f) {
  unsigned u = __float_as_uint(f);
  u += 0x7FFF + ((u >> 16) & 1);  // round-to-nearest-even
  return (short)(u >> 16);
}
__device__ __forceinline__ float bf2f(unsigned short u) {
  return __uint_as_float(((unsigned)u) << 16);
}

// ---------------------------------------------------------------------------
// Kernel 1: CSR row pointers from sorted row_idx (binary search).
// ---------------------------------------------------------------------------
__global__ __launch_bounds__(256) void build_row_ptr_kernel(
    const int* __restrict__ row_idx, int* __restrict__ row_ptr) {
  int i = blockIdx.x * blockDim.x + threadIdx.x;
  if (i > N_NODES) return;
  int lo = 0, hi = N_EDGES;
  while (lo < hi) {
    int mid = (lo + hi) >> 1;
    if (row_idx[mid] < i) lo = mid + 1; else hi = mid;
  }
  row_ptr[i] = lo;
}

// ---------------------------------------------------------------------------
// Kernel 1b: precompute W as bf16 MFMA B-fragments, fragment-major.
//   k = s*32 + (l>>4)*8 + j, col = t*16 + (l&15)
// ---------------------------------------------------------------------------
__global__ __launch_bounds__(256) void wfrag_kernel(
    const float* __restrict__ W, short* __restrict__ Wf) {
  int tid = blockIdx.x * blockDim.x + threadIdx.x;  // [0, 2048)
  if (tid >= 2048) return;
  int s = tid >> 8;
  int r = tid & 255;
  int t = r >> 6;
  int lane = r & 63;
  int col = t * 16 + (lane & 15);
  int kbase = s * 32 + ((lane >> 4) & 3) * 8;
#pragma unroll
  for (int j = 0; j < 8; ++j) {
    Wf[(size_t)tid * 8 + j] = f2bf(W[(size_t)(kbase + j) * OUT_F + col]);
  }
}

// ---------------------------------------------------------------------------
// Kernel 2: support(bf16) = x @ W via bf16 MFMA (16x16x32).
// Block = 4 waves, 64 rows. Wave w: rows [b*64+w*16,+16) x all 64 cols.
// Epilogue converts fp32 acc -> bf16 and stores to supB.
// C/D layout (HW-verified): col = lane&15, row = (lane>>4)*4 + reg.
// ---------------------------------------------------------------------------
__global__ __launch_bounds__(256) void gemm_kernel(
    const float* __restrict__ x, const short* __restrict__ Wf,
    unsigned short* __restrict__ supB) {
  __shared__ short sWf[8 * 4 * 64 * 8];  // 32 KB
  {
    const float4* g = reinterpret_cast<const float4*>(Wf);
    float4* s4 = reinterpret_cast<float4*>(sWf);
#pragma unroll
    for (int i = 0; i < 8; ++i) s4[threadIdx.x + i * 256] = g[threadIdx.x + i * 256];
  }
  __syncthreads();

  const int lane = threadIdx.x & 63;
  const int wave = threadIdx.x >> 6;
  const int r0_base = blockIdx.x * 64 + wave * 16;

  int arow = r0_base + (lane & 15);
  if (arow >= N_NODES) arow = N_NODES - 1;
  const float* xrow = x + (size_t)arow * IN_F + ((lane >> 4) & 3) * 8;

  f32x4 acc0 = {0.f, 0.f, 0.f, 0.f};
  f32x4 acc1 = {0.f, 0.f, 0.f, 0.f};
  f32x4 acc2 = {0.f, 0.f, 0.f, 0.f};
  f32x4 acc3 = {0.f, 0.f, 0.f, 0.f};

#pragma unroll
  for (int s = 0; s < 8; ++s) {
    const float4 f0 = *reinterpret_cast<const float4*>(xrow + s * 32);
    const float4 f1 = *reinterpret_cast<const float4*>(xrow + s * 32 + 4);
    bf16x8 a;
    a[0] = f2bf(f0.x); a[1] = f2bf(f0.y); a[2] = f2bf(f0.z); a[3] = f2bf(f0.w);
    a[4] = f2bf(f1.x); a[5] = f2bf(f1.y); a[6] = f2bf(f1.z); a[7] = f2bf(f1.w);
    const bf16x8 b0 = *reinterpret_cast<const bf16x8*>(&sWf[((s * 4 + 0) * 64 + lane) * 8]);
    const bf16x8 b1 = *reinterpret_cast<const bf16x8*>(&sWf[((s * 4 + 1) * 64 + lane) * 8]);
    const bf16x8 b2 = *reinterpret_cast<const bf16x8*>(&sWf[((s * 4 + 2) * 64 + lane) * 8]);
    const bf16x8 b3 = *reinterpret_cast<const bf16x8*>(&sWf[((s * 4 + 3) * 64 + lane) * 8]);
    acc0 = __builtin_amdgcn_mfma_f32_16x16x32_bf16(a, b0, acc0, 0, 0, 0);
    acc1 = __builtin_amdgcn_mfma_f32_16x16x32_bf16(a, b1, acc1, 0, 0, 0);
    acc2 = __builtin_amdgcn_mfma_f32_16x16x32_bf16(a, b2, acc2, 0, 0, 0);
    acc3 = __builtin_amdgcn_mfma_f32_16x16x32_bf16(a, b3, acc3, 0, 0, 0);
  }

  const int orow_base = r0_base + ((lane >> 4) & 3) * 4;
  const int ocol = lane & 15;
#pragma unroll
  for (int r = 0; r < 4; ++r) {
    const int row = orow_base + r;
    if (row < N_NODES) {
      unsigned short* o = supB + (size_t)row * OUT_F + ocol;
      o[0]  = (unsigned short)f2bf(acc0[r]);
      o[16] = (unsigned short)f2bf(acc1[r]);
      o[32] = (unsigned short)f2bf(acc2[r]);
      o[48] = (unsigned short)f2bf(acc3[r]);
    }
  }
}

// ---------------------------------------------------------------------------
// Kernel 3: out[n] = bias + sum_{e in row n} ev[e] * supB[col[e]]  (bf16 gather)
// One wave per node. lane -> (g = lane>>4: edge subgroup, fq = lane&15:
// feature quad). Each lane loads 8 B (4 bf16 features) of edge i+g -> one
// load instruction covers 4 edges; unroll x2 = 8 edges in flight.
// Cross-g reduce via 2 shfl_xor; lanes 0-15 store one coalesced float4.
// Deterministic, no atomics.
// ---------------------------------------------------------------------------
__global__ __launch_bounds__(256) void spmm_kernel(
    const unsigned short* __restrict__ supB, const float* __restrict__ ev,
    const int* __restrict__ col, const int* __restrict__ row_ptr,
    const float* __restrict__ bias, float* __restrict__ out) {
  const int lane = threadIdx.x & 63;
  const int g = lane >> 4;
  const int fq = lane & 15;
  const int gwave = (blockIdx.x * blockDim.x + threadIdx.x) >> 6;
  const int nwaves = (gridDim.x * blockDim.x) >> 6;

  const float b0 = bias[fq * 4 + 0];
  const float b1 = bias[fq * 4 + 1];
  const float b2 = bias[fq * 4 + 2];
  const float b3 = bias[fq * 4 + 3];

  for (int node = gwave; node < N_NODES; node += nwaves) {
    const int s = row_ptr[node];
    const int e = row_ptr[node + 1];
    float a0 = 0.f, a1 = 0.f, a2 = 0.f, a3 = 0.f;

    for (int i = s; i < e; i += 8) {
      const int i0 = i + g;
      const int i1 = i + 4 + g;
      const bool p0 = i0 < e;
      const bool p1 = i1 < e;
      const int c0 = p0 ? col[i0] : 0;
      const int c1 = p1 ? col[i1] : 0;
      const float v0 = p0 ? ev[i0] : 0.f;
      const float v1 = p1 ? ev[i1] : 0.f;
      const ushort4 s0 = *reinterpret_cast<const ushort4*>(supB + (size_t)c0 * OUT_F + fq * 4);
      const ushort4 s1 = *reinterpret_cast<const ushort4*>(supB + (size_t)c1 * OUT_F + fq * 4);
      a0 = fmaf(v0, bf2f(s0.x), a0);
      a1 = fmaf(v0, bf2f(s0.y), a1);
      a2 = fmaf(v0, bf2f(s0.z), a2);
      a3 = fmaf(v0, bf2f(s0.w), a3);
      a0 = fmaf(v1, bf2f(s1.x), a0);
      a1 = fmaf(v1, bf2f(s1.y), a1);
      a2 = fmaf(v1, bf2f(s1.z), a2);
      a3 = fmaf(v1, bf2f(s1.w), a3);
    }

    // reduce across the 4 edge subgroups (lanes differing in bits 4,5)
    a0 += __shfl_xor(a0, 16); a0 += __shfl_xor(a0, 32);
    a1 += __shfl_xor(a1, 16); a1 += __shfl_xor(a1, 32);
    a2 += __shfl_xor(a2, 16); a2 += __shfl_xor(a2, 32);
    a3 += __shfl_xor(a3, 16); a3 += __shfl_xor(a3, 32);

    if (lane < 16) {
      float4 o;
      o.x = a0 + b0; o.y = a1 + b1; o.z = a2 + b2; o.w = a3 + b3;
      *reinterpret_cast<float4*>(out + (size_t)node * OUT_F + fq * 4) = o;
    }
  }
}

extern "C" void kernel_launch(void* const* d_in, const int* in_sizes, int n_in,
                              void* d_out, int out_size, void* d_ws, size_t ws_size,
                              hipStream_t stream) {
  const float* x        = (const float*)d_in[0];
  const float* ev       = (const float*)d_in[1];
  const float* W        = (const float*)d_in[2];
  const float* bias     = (const float*)d_in[3];
  const int*   row_idx  = (const int*)d_in[4];
  const int*   col_idx  = (const int*)d_in[5];
  float* out = (float*)d_out;

  // Workspace: [0, 400KB) row_ptr; [448KB, 480KB) W-fragments (bf16);
  //            [512KB, +12.8MB) support bf16.
  int*            row_ptr = (int*)d_ws;
  short*          Wf      = (short*)((char*)d_ws + 448 * 1024);
  unsigned short* supB    = (unsigned short*)((char*)d_ws + 512 * 1024);

  build_row_ptr_kernel<<<(N_NODES + 1 + 255) / 256, 256, 0, stream>>>(row_idx, row_ptr);
  wfrag_kernel<<<8, 256, 0, stream>>>(W, Wf);

  gemm_kernel<<<(N_NODES + 63) / 64, 256, 0, stream>>>(x, Wf, supB);

  spmm_kernel<<<2048, 256, 0, stream>>>(supB, ev, col_idx, row_ptr, bias, out);
}